// Round 4
// baseline (68.401 us; speedup 1.0000x reference)
//
#include <hip/hip_runtime.h>

// SimpleSNN: out[r][j] = sum over 10 steps of spikes from a leaky neuron driven by
// cur[r][j] = dot(x[r,:], W[j,:]).  x:[65536,784] f32, W:[10,784] f32, out f32.
//
// R4: barrier-free streaming. R3 (48.5us) was stall-bound: 49 syncthreads/block and
// s_load(W)+ds_read(x) sharing lgkmcnt serialized the inner loop. Now:
//  - block = 256 threads = 4 waves over 64 rows; wave q owns col-quarter q of lane-
//    row l. q is wave-uniform -> W reads stay scalar (s_load, K$ broadcast).
//  - W pre-transposed to f64 W64T[c][j] in d_ws: every W access = base + imm offset.
//  - x: each lane streams its 196 cols as 49 float4 loads (imm offsets), prefetch
//    one chunk ahead. No LDS staging, no tile barriers.
//  - single __syncthreads: 20KB LDS combine of 4 quarter-partials, then recurrence.
//  - f64 products/accum/recurrence kept bit-identical in structure to R1/R3
//    (absmax == 0.0 both rounds; threshold crossings are the hazard).

constexpr int ROWS  = 65536;
constexpr int COLS  = 784;
constexpr int NOUT  = 10;
constexpr int STEPS = 10;

constexpr int QN  = 4;          // quarters per row = waves per block
constexpr int QC  = COLS / QN;  // 196 cols per quarter
constexpr int NIT = QC / 4;     // 49 float4 chunks per quarter
constexpr int BRW = 64;         // rows per block (one per lane)

__global__ void w_prep(const float* __restrict__ W, double* __restrict__ W64T) {
    int i = blockIdx.x * 256 + threadIdx.x;   // i = c*10 + j
    if (i < NOUT * COLS) {
        int c = i / NOUT, j = i - c * NOUT;
        W64T[i] = (double)W[(size_t)j * COLS + c];
    }
}

__global__ __launch_bounds__(256, 4)
void snn_stream(const float* __restrict__ x, const double* __restrict__ W64T,
                float* __restrict__ out) {
    __shared__ double part[QN * BRW * NOUT];            // 20 KB

    const int tid = threadIdx.x;
    const int l   = tid & 63;                           // lane -> row within block
    const int q   = __builtin_amdgcn_readfirstlane(tid >> 6);  // wave -> quarter
    const size_t row0 = (size_t)blockIdx.x * BRW;

    const float*  xp = x + (row0 + l) * COLS + q * QC;  // per-lane base; 16B aligned
    const double* wp = W64T + q * QC * NOUT;            // wave-uniform base

    double acc[NOUT];
    #pragma unroll
    for (int j = 0; j < NOUT; ++j) acc[j] = 0.0;

    float4 cur = *reinterpret_cast<const float4*>(xp);
    #pragma unroll 7
    for (int it = 0; it < NIT; ++it) {
        int itn = (it + 1 < NIT) ? it + 1 : NIT - 1;    // clamp: last prefetch benign
        float4 nxt = *reinterpret_cast<const float4*>(xp + itn * 4);
        const double* wb = wp + it * 4 * NOUT;          // s_load base+imm
        #pragma unroll
        for (int c = 0; c < 4; ++c) {
            double xd = (double)((&cur.x)[c]);
            #pragma unroll
            for (int j = 0; j < NOUT; ++j)
                acc[j] = fma(xd, wb[c * NOUT + j], acc[j]);
        }
        cur = nxt;
    }

    #pragma unroll
    for (int j = 0; j < NOUT; ++j)
        part[(q * BRW + l) * NOUT + j] = acc[j];
    __syncthreads();                                    // the only barrier

    for (int i = tid; i < BRW * NOUT; i += 256) {       // 640 outputs, 256 threads
        double c0  = part[i]                 + part[BRW * NOUT + i];
        double c1  = part[2 * BRW * NOUT + i] + part[3 * BRW * NOUT + i];
        double cur = c0 + c1;

        double mem = 0.0, spk = 0.0, s = 0.0;
        #pragma unroll
        for (int st = 0; st < STEPS; ++st) {
            mem = 0.95 * mem + cur - spk;               // reset-by-subtraction, thr=1.0
            spk = (mem > 1.0) ? 1.0 : 0.0;
            s  += spk;
        }
        out[row0 * NOUT + i] = (float)s;                // consecutive lanes -> coalesced
    }
}

extern "C" void kernel_launch(void* const* d_in, const int* in_sizes, int n_in,
                              void* d_out, int out_size, void* d_ws, size_t ws_size,
                              hipStream_t stream) {
    const float* x = (const float*)d_in[0];
    const float* W = (const float*)d_in[1];
    float*  out  = (float*)d_out;
    double* W64T = (double*)d_ws;   // 7840 * 8B = 62.7 KB

    hipLaunchKernelGGL(w_prep, dim3((NOUT * COLS + 255) / 256), dim3(256), 0, stream, W, W64T);
    hipLaunchKernelGGL(snn_stream, dim3(ROWS / BRW), dim3(256), 0, stream, x, W64T, out);
}